// Round 2
// baseline (387.461 us; speedup 1.0000x reference)
//
#include <hip/hip_runtime.h>

#define D 128
#define S 16

// K1: attention + neighbor aggregation. 8 elements/block (32 lanes each),
// grid 1024 -> 16 waves/CU to hide gather latency. msg (f32) -> d_ws.
__global__ __launch_bounds__(256) void k1_attn(
    const int* __restrict__ u, const int* __restrict__ v,
    const int* __restrict__ adj_ent, const int* __restrict__ adj_rel,
    const float* __restrict__ usr, const float* __restrict__ ent,
    const float* __restrict__ rel, float* __restrict__ msg_out)
{
    const int tid  = threadIdx.x;
    const int grp  = tid >> 5;      // element slot 0..7
    const int lane = tid & 31;      // 32 lanes per element, 4 dims each
    const int b    = blockIdx.x * 8 + grp;

    const int uu = u[b];
    const int vv = v[b];

    const float4 u4 = *(const float4*)(usr + (size_t)uu * D + lane * 4);

    // lanes 0..15 hold the adjacency row; shuffled out per s
    const int ae = adj_ent[(size_t)vv * S + (lane & 15)];
    const int ar = adj_rel[(size_t)vv * S + (lane & 15)];

    float sc[S];
    #pragma unroll
    for (int s = 0; s < S; ++s) {
        const int nr = __shfl(ar, s, 32);
        const float4 r4 = *(const float4*)(rel + (size_t)nr * D + lane * 4);
        float p = u4.x * r4.x + u4.y * r4.y + u4.z * r4.z + u4.w * r4.w;
        #pragma unroll
        for (int off = 16; off >= 1; off >>= 1) p += __shfl_xor(p, off, 32);
        sc[s] = p;                  // replicated across the 32-lane group
    }

    float mx = sc[0];
    #pragma unroll
    for (int s = 1; s < S; ++s) mx = fmaxf(mx, sc[s]);
    float sum = 0.f;
    #pragma unroll
    for (int s = 0; s < S; ++s) { sc[s] = __expf(sc[s] - mx); sum += sc[s]; }
    const float inv = 1.f / sum;

    float m0 = 0.f, m1 = 0.f, m2 = 0.f, m3 = 0.f;
    #pragma unroll
    for (int s = 0; s < S; ++s) {
        const int ne = __shfl(ae, s, 32);
        const float4 n4 = *(const float4*)(ent + (size_t)ne * D + lane * 4);
        const float a = sc[s] * inv;
        m0 += a * n4.x; m1 += a * n4.y; m2 += a * n4.z; m3 += a * n4.w;
    }
    *(float4*)(msg_out + (size_t)b * D + lane * 4) = make_float4(m0, m1, m2, m3);
}

// K2: two relu((msg+rep)@W+b) layers + fused final dot/sigmoid.
// 32 elements/block, grid 256. LDS: msg/X/R = 48 KB. Matmul: 4x4 register
// tile per thread; x reads are 2-way LDS broadcasts (free), W row slice
// (16 B) is L1/L2-resident after first block touches it.
__global__ __launch_bounds__(256) void k2_layers(
    const int* __restrict__ u, const int* __restrict__ v,
    const float* __restrict__ usr, const float* __restrict__ ent,
    const float* __restrict__ W, const float* __restrict__ bias,
    const float* __restrict__ msg_in, float* __restrict__ out)
{
    __shared__ float sMsg[32 * D];
    __shared__ float sX[32 * D];
    __shared__ float sR[32 * D];

    const int tid = threadIdx.x;
    const int b0  = blockIdx.x * 32;

    // stage msg (f32, coalesced float4)
    {
        const float4* src = (const float4*)(msg_in + (size_t)b0 * D);
        float4* dst = (float4*)sMsg;
        #pragma unroll
        for (int k = 0; k < 4; ++k) dst[k * 256 + tid] = src[k * 256 + tid];
    }
    // gather rep0 = ent_table[v]
    {
        const int grp = tid >> 5, lane = tid & 31;
        #pragma unroll
        for (int p = 0; p < 4; ++p) {
            const int e  = p * 8 + grp;
            const int vv = v[b0 + e];
            *(float4*)&sR[e * D + lane * 4] =
                *(const float4*)(ent + (size_t)vv * D + lane * 4);
        }
    }
    __syncthreads();

    const int mg = tid >> 5, jg = tid & 31;
    const int m0 = mg * 4, j0 = jg * 4;
    float bf[4];
    #pragma unroll
    for (int c = 0; c < 4; ++c) bf[c] = bias[j0 + c];

    for (int it = 0; it < 2; ++it) {
        // X = msg + R
        #pragma unroll
        for (int k = 0; k < 16; ++k) {
            const int idx = k * 256 + tid;
            sX[idx] = sMsg[idx] + sR[idx];
        }
        __syncthreads();

        float acc[4][4];
        #pragma unroll
        for (int k = 0; k < 4; ++k)
            #pragma unroll
            for (int c = 0; c < 4; ++c) acc[k][c] = 0.f;

        #pragma unroll 4
        for (int d = 0; d < D; ++d) {
            const float4 w4 = *(const float4*)(W + d * D + j0);
            #pragma unroll
            for (int k = 0; k < 4; ++k) {
                const float xm = sX[(m0 + k) * D + d];
                acc[k][0] += xm * w4.x; acc[k][1] += xm * w4.y;
                acc[k][2] += xm * w4.z; acc[k][3] += xm * w4.w;
            }
        }

        // R = relu(acc + b)  (matmul reads sX only; sR not read during matmul)
        #pragma unroll
        for (int k = 0; k < 4; ++k) {
            float4 y;
            y.x = fmaxf(acc[k][0] + bf[0], 0.f);
            y.y = fmaxf(acc[k][1] + bf[1], 0.f);
            y.z = fmaxf(acc[k][2] + bf[2], 0.f);
            y.w = fmaxf(acc[k][3] + bf[3], 0.f);
            *(float4*)&sR[(m0 + k) * D + j0] = y;
        }
        __syncthreads();
    }

    // out = sigmoid(u_emb . rep2)
    #pragma unroll
    for (int p = 0; p < 4; ++p) {
        const int e  = p * 8 + mg;
        const int bb = b0 + e;
        const int uu = u[bb];
        const float4 u4 = *(const float4*)(usr + (size_t)uu * D + jg * 4);
        const float4 rf = *(const float4*)&sR[e * D + jg * 4];
        float pr = u4.x * rf.x + u4.y * rf.y + u4.z * rf.z + u4.w * rf.w;
        #pragma unroll
        for (int off = 16; off >= 1; off >>= 1) pr += __shfl_xor(pr, off, 32);
        if (jg == 0) out[bb] = 1.f / (1.f + __expf(-pr));
    }
}

extern "C" void kernel_launch(void* const* d_in, const int* in_sizes, int n_in,
                              void* d_out, int out_size, void* d_ws, size_t ws_size,
                              hipStream_t stream)
{
    const int* u       = (const int*)d_in[0];
    const int* v       = (const int*)d_in[1];
    const int* adj_ent = (const int*)d_in[2];
    const int* adj_rel = (const int*)d_in[3];
    const float* usr   = (const float*)d_in[4];
    const float* ent   = (const float*)d_in[5];
    const float* rel   = (const float*)d_in[6];
    const float* W     = (const float*)d_in[7];
    const float* bias  = (const float*)d_in[8];

    float* msg_ws = (float*)d_ws;              // 8192*128*4 = 4 MiB scratch
    float* out = (float*)d_out;

    hipLaunchKernelGGL(k1_attn, dim3(8192 / 8), dim3(256), 0, stream,
                       u, v, adj_ent, adj_rel, usr, ent, rel, msg_ws);
    hipLaunchKernelGGL(k2_layers, dim3(8192 / 32), dim3(256), 0, stream,
                       u, v, usr, ent, W, bias, msg_ws, out);
}

// Round 3
// 385.166 us; speedup vs baseline: 1.0060x; 1.0060x over previous
//
#include <hip/hip_runtime.h>

#define D 128
#define S 16

// K1: attention + neighbor aggregation. 8 elements/block (32 lanes each),
// grid 1024 -> 16 waves/CU. Gathers chunked 2x8 to cap live VGPRs while
// keeping 8 loads in flight (Little's law: 16 waves x 8 KB >> 9 KB/CU needed
// to saturate the per-CU HBM share). msg (f32) -> d_ws.
__global__ __launch_bounds__(256) void k1_attn(
    const int* __restrict__ u, const int* __restrict__ v,
    const int* __restrict__ adj_ent, const int* __restrict__ adj_rel,
    const float* __restrict__ usr, const float* __restrict__ ent,
    const float* __restrict__ rel, float* __restrict__ msg_out)
{
    const int tid  = threadIdx.x;
    const int grp  = tid >> 5;      // element slot 0..7
    const int lane = tid & 31;      // 32 lanes per element, 4 dims each
    const int b    = blockIdx.x * 8 + grp;

    const int uu = u[b];
    const int vv = v[b];

    const float4 u4 = *(const float4*)(usr + (size_t)uu * D + lane * 4);

    // lanes 0..15 hold the adjacency row; shuffled out per s
    const int ae = adj_ent[(size_t)vv * S + (lane & 15)];
    const int ar = adj_rel[(size_t)vv * S + (lane & 15)];

    float sc[S];
    #pragma unroll
    for (int h = 0; h < 2; ++h) {
        float4 r4[8];
        #pragma unroll
        for (int s = 0; s < 8; ++s) {
            const int nr = __shfl(ar, h * 8 + s, 32);
            r4[s] = *(const float4*)(rel + (size_t)nr * D + lane * 4);
        }
        #pragma unroll
        for (int s = 0; s < 8; ++s) {
            float p = u4.x * r4[s].x + u4.y * r4[s].y +
                      u4.z * r4[s].z + u4.w * r4[s].w;
            #pragma unroll
            for (int off = 16; off >= 1; off >>= 1) p += __shfl_xor(p, off, 32);
            sc[h * 8 + s] = p;      // replicated across the 32-lane group
        }
    }

    float mx = sc[0];
    #pragma unroll
    for (int s = 1; s < S; ++s) mx = fmaxf(mx, sc[s]);
    float sum = 0.f;
    #pragma unroll
    for (int s = 0; s < S; ++s) { sc[s] = __expf(sc[s] - mx); sum += sc[s]; }
    const float inv = 1.f / sum;

    float m0 = 0.f, m1 = 0.f, m2 = 0.f, m3 = 0.f;
    #pragma unroll
    for (int h = 0; h < 2; ++h) {
        float4 n4[8];
        #pragma unroll
        for (int s = 0; s < 8; ++s) {
            const int ne = __shfl(ae, h * 8 + s, 32);
            n4[s] = *(const float4*)(ent + (size_t)ne * D + lane * 4);
        }
        #pragma unroll
        for (int s = 0; s < 8; ++s) {
            const float a = sc[h * 8 + s] * inv;
            m0 += a * n4[s].x; m1 += a * n4[s].y;
            m2 += a * n4[s].z; m3 += a * n4[s].w;
        }
    }
    *(float4*)(msg_out + (size_t)b * D + lane * 4) = make_float4(m0, m1, m2, m3);
}

// K2: two relu((msg+rep)@W+b) layers + fused final dot/sigmoid.
// 16 elements/block, grid 512 -> 2 blocks/CU (was 1: zero TLP + full tail).
// 2x4 register tile: per wave per d, 2 ds_read (~11.6 cyc) vs 16 v_fmac
// (32 cyc) -> still VALU-bound. LDS 24 KB/block. 2-way same-bank LDS alias
// on the xm reads is free (m136).
__global__ __launch_bounds__(256) void k2_layers(
    const int* __restrict__ u, const int* __restrict__ v,
    const float* __restrict__ usr, const float* __restrict__ ent,
    const float* __restrict__ W, const float* __restrict__ bias,
    const float* __restrict__ msg_in, float* __restrict__ out)
{
    __shared__ float sMsg[16 * D];
    __shared__ float sX[16 * D];
    __shared__ float sR[16 * D];

    const int tid = threadIdx.x;
    const int b0  = blockIdx.x * 16;

    // stage msg (f32, coalesced float4): 512 float4 / 256 threads = 2 each
    {
        const float4* src = (const float4*)(msg_in + (size_t)b0 * D);
        float4* dst = (float4*)sMsg;
        #pragma unroll
        for (int k = 0; k < 2; ++k) dst[k * 256 + tid] = src[k * 256 + tid];
    }
    // gather rep0 = ent_table[v]: 16 elems, 32 lanes each
    {
        const int grp = tid >> 5, lane = tid & 31;
        #pragma unroll
        for (int p = 0; p < 2; ++p) {
            const int e  = p * 8 + grp;
            const int vv = v[b0 + e];
            *(float4*)&sR[e * D + lane * 4] =
                *(const float4*)(ent + (size_t)vv * D + lane * 4);
        }
    }
    __syncthreads();

    const int mg = tid >> 5, jg = tid & 31;
    const int m0 = mg * 2, j0 = jg * 4;
    float bf[4];
    #pragma unroll
    for (int c = 0; c < 4; ++c) bf[c] = bias[j0 + c];

    for (int it = 0; it < 2; ++it) {
        // X = msg + R: 2048 floats / 256 threads = 8 each
        #pragma unroll
        for (int k = 0; k < 8; ++k) {
            const int idx = k * 256 + tid;
            sX[idx] = sMsg[idx] + sR[idx];
        }
        __syncthreads();

        float acc[2][4];
        #pragma unroll
        for (int k = 0; k < 2; ++k)
            #pragma unroll
            for (int c = 0; c < 4; ++c) acc[k][c] = 0.f;

        #pragma unroll 4
        for (int d = 0; d < D; ++d) {
            const float4 w4 = *(const float4*)(W + d * D + j0);
            #pragma unroll
            for (int k = 0; k < 2; ++k) {
                const float xm = sX[(m0 + k) * D + d];
                acc[k][0] += xm * w4.x; acc[k][1] += xm * w4.y;
                acc[k][2] += xm * w4.z; acc[k][3] += xm * w4.w;
            }
        }

        // R = relu(acc + b)  (matmul reads sX only; sR not read during matmul)
        #pragma unroll
        for (int k = 0; k < 2; ++k) {
            float4 y;
            y.x = fmaxf(acc[k][0] + bf[0], 0.f);
            y.y = fmaxf(acc[k][1] + bf[1], 0.f);
            y.z = fmaxf(acc[k][2] + bf[2], 0.f);
            y.w = fmaxf(acc[k][3] + bf[3], 0.f);
            *(float4*)&sR[(m0 + k) * D + j0] = y;
        }
        __syncthreads();
    }

    // out = sigmoid(u_emb . rep2)
    #pragma unroll
    for (int p = 0; p < 2; ++p) {
        const int e  = p * 8 + mg;
        const int bb = b0 + e;
        const int uu = u[bb];
        const float4 u4 = *(const float4*)(usr + (size_t)uu * D + jg * 4);
        const float4 rf = *(const float4*)&sR[e * D + jg * 4];
        float pr = u4.x * rf.x + u4.y * rf.y + u4.z * rf.z + u4.w * rf.w;
        #pragma unroll
        for (int off = 16; off >= 1; off >>= 1) pr += __shfl_xor(pr, off, 32);
        if (jg == 0) out[bb] = 1.f / (1.f + __expf(-pr));
    }
}

extern "C" void kernel_launch(void* const* d_in, const int* in_sizes, int n_in,
                              void* d_out, int out_size, void* d_ws, size_t ws_size,
                              hipStream_t stream)
{
    const int* u       = (const int*)d_in[0];
    const int* v       = (const int*)d_in[1];
    const int* adj_ent = (const int*)d_in[2];
    const int* adj_rel = (const int*)d_in[3];
    const float* usr   = (const float*)d_in[4];
    const float* ent   = (const float*)d_in[5];
    const float* rel   = (const float*)d_in[6];
    const float* W     = (const float*)d_in[7];
    const float* bias  = (const float*)d_in[8];

    float* msg_ws = (float*)d_ws;              // 8192*128*4 = 4 MiB scratch
    float* out = (float*)d_out;

    hipLaunchKernelGGL(k1_attn, dim3(8192 / 8), dim3(256), 0, stream,
                       u, v, adj_ent, adj_rel, usr, ent, rel, msg_ws);
    hipLaunchKernelGGL(k2_layers, dim3(8192 / 16), dim3(256), 0, stream,
                       u, v, usr, ent, W, bias, msg_ws, out);
}